// Round 7
// baseline (1203.000 us; speedup 1.0000x reference)
//
#include <hip/hip_runtime.h>
#include <hip/hip_bf16.h>
#include <math.h>

// GGNN: N=50000 nodes, E=400000 edges, G=64 graphs, IN=64, OUT=128, 4 etypes, 8 steps.
// R12: wave-uniform segmented gather (software-pipelined), R11 gates kept.
//   hx[N][256] fp16: cols 0..127 = ab (aggregated msg), cols 128..255 = hb (h shadow).
//   k_agg_gemm (256 thr, 32 rows): wave w walks the contiguous edge range of nodes
//     [m0+w*8, m0+w*8+8): ALL 64 lanes on the same edge (f16x2/lane = coalesced 256B),
//     per-lane f32 accumulator, flush to LDS s-plane on (dst,et)-key change (key is
//     packed in the edge word: src | et<<16 | (dst&31)<<18; wave-uniform branch).
//     Chunks of 8 edges: 8 key loads + 8 value loads in flight, next chunk's keys
//     prefetched during processing (static indices only). Then K=512 MFMA vs Wcat,
//     + cnt*bs epilogue -> ab half of hx.  (R11: 4-loads-in-flight per-thread walk +
//     64 predicated VALU/edge-thread = 86us latency-bound; this removes both.)
//   k_gates_gru (512 thr, 64 rows, 70.7KB LDS): unchanged from R11 (proven ~49us).

#define NN 50000
#define NE 400000
#define NG 64
#define IND 64
#define OD 128
#define NN4 (NN * 4)
#define RC 8      // readout chunks per graph

typedef _Float16 f16x8 __attribute__((ext_vector_type(8)));
typedef _Float16 f16x4 __attribute__((ext_vector_type(4)));
typedef _Float16 f16x2 __attribute__((ext_vector_type(2)));
typedef float f32x4 __attribute__((ext_vector_type(4)));

__device__ inline unsigned short f2h(float x) {
    _Float16 hv = (_Float16)x;
    unsigned short u;
    __builtin_memcpy(&u, &hv, 2);
    return u;
}

// ---------------- Ws fp32 -> concatenated fp16 Wcat[o][t*128+k] ----------------
__global__ void k_cvtws(const float* __restrict__ Ws, unsigned short* __restrict__ Wcat) {
    int i = blockIdx.x * 256 + threadIdx.x;   // 65536
    if (i >= 65536) return;
    int o = i >> 9, col = i & 511;
    int t = col >> 7, k = col & 127;
    Wcat[i] = f2h(Ws[t * 16384 + o * 128 + k]);
}

// ---------------- pack GRU weights into 6 stage-chunks of 128x128 fp16 ----------------
// chunk c: rows (c>>1)*128..+128 of (c&1 ? W_hh : W_ih)
//   c0=R_ih c1=R_hh c2=Z_ih c3=Z_hh c4=IN_ih c5=HN_hh
// bpk[0..255] = b_ih+b_hh (r,z), bpk[256..383] = b_ih[256..], bpk[384..511] = b_hh[256..]
__global__ void k_pack(const float* __restrict__ Wih, const float* __restrict__ Whh,
                       const float* __restrict__ bih, const float* __restrict__ bhh,
                       unsigned short* __restrict__ Wpk, float* __restrict__ bpk) {
    int i = blockIdx.x * 256 + threadIdx.x;
    if (i < 98304) {
        int c = i >> 14, j = i & 16383, o = j >> 7, k = j & 127;
        const float* W = (c & 1) ? Whh : Wih;
        Wpk[i] = f2h(W[((c >> 1) * 128 + o) * 128 + k]);
    }
    if (i < 512) {
        float b;
        if (i < 256) b = bih[i] + bhh[i];
        else if (i < 384) b = bih[i];
        else b = bhh[i - 128];
        bpk[i] = b;
    }
}

// ---------------- init h = [node_features | 0] (fp32 + fp16 shadow in hx) -------------
__global__ void k_init_h(const float* __restrict__ nf, float* __restrict__ h,
                         unsigned short* __restrict__ hx) {
    int i = blockIdx.x * 256 + threadIdx.x;
    if (i >= NN * OD) return;
    int n = i >> 7, d = i & 127;
    float v = (d < IND) ? nf[n * IND + d] : 0.f;
    h[i] = v;
    hx[(size_t)n * 256 + 128 + d] = f2h(v);
}

// ---------------- (dst, etype) CSR build: 200000 segments ----------------
__global__ void k_count(const int* __restrict__ dst, const int* __restrict__ et,
                        int* __restrict__ deg4) {
    int e = blockIdx.x * 256 + threadIdx.x;
    if (e < NE) atomicAdd(&deg4[dst[e] * 4 + et[e]], 1);
}

__global__ void k_scan1(const int* __restrict__ deg, int* __restrict__ rowp,
                        int* __restrict__ bsum, int n) {
    __shared__ int buf[1024];
    int tid = threadIdx.x;
    int i = blockIdx.x * 1024 + tid;
    int v = (i < n) ? deg[i] : 0;
    buf[tid] = v;
    __syncthreads();
    for (int off = 1; off < 1024; off <<= 1) {
        int t = (tid >= off) ? buf[tid - off] : 0;
        __syncthreads();
        buf[tid] += t;
        __syncthreads();
    }
    if (i < n) rowp[i + 1] = buf[tid];
    if (tid == 1023) bsum[blockIdx.x] = buf[tid];
}

__global__ void k_scan2(int* __restrict__ bsum, int nb) {
    __shared__ int buf[256];
    int tid = threadIdx.x;
    int v = (tid < nb) ? bsum[tid] : 0;
    buf[tid] = v;
    __syncthreads();
    for (int off = 1; off < 256; off <<= 1) {
        int t = (tid >= off) ? buf[tid - off] : 0;
        __syncthreads();
        buf[tid] += t;
        __syncthreads();
    }
    if (tid < nb) bsum[tid] = buf[tid] - v;   // exclusive
}

__global__ void k_scan3(const int* __restrict__ deg, const int* __restrict__ bsum,
                        int* __restrict__ rowp, int* __restrict__ cursor, int n) {
    int i = blockIdx.x * 256 + threadIdx.x;
    if (i >= n) return;
    int incl = rowp[i + 1] + bsum[i >> 10];
    rowp[i + 1] = incl;
    cursor[i] = incl - deg[i];
    if (i == 0) rowp[0] = 0;
}

__global__ void k_fill(const int* __restrict__ src, const int* __restrict__ dst,
                       const int* __restrict__ et, int* __restrict__ cursor,
                       int* __restrict__ epk) {
    int e = blockIdx.x * 256 + threadIdx.x;
    if (e < NE) {
        int t = et[e];
        int d = dst[e];
        int pos = atomicAdd(&cursor[d * 4 + t], 1);
        // src (16b) | et (2b) | dst&31 (5b): key = word>>16 is unique per (dst,et)
        // within any 32-aligned node tile.
        epk[pos] = src[e] | (t << 16) | ((d & 31) << 18);
    }
}

// ---------------- graph CSR build (by graph id), for readout ----------------
__global__ void k_gcount(const int* __restrict__ gid, int* __restrict__ gdeg) {
    __shared__ int c[NG];
    int tid = threadIdx.x;
    if (tid < NG) c[tid] = 0;
    __syncthreads();
    int n = blockIdx.x * 1024 + tid;
    if (n < NN) atomicAdd(&c[gid[n]], 1);
    __syncthreads();
    if (tid < NG && c[tid] > 0) atomicAdd(&gdeg[tid], c[tid]);
}

__global__ void k_gscan(const int* __restrict__ gdeg, int* __restrict__ growp,
                        int* __restrict__ gcur) {
    __shared__ int buf[NG];
    int tid = threadIdx.x;
    int v = gdeg[tid];
    buf[tid] = v;
    __syncthreads();
    for (int off = 1; off < NG; off <<= 1) {
        int t = (tid >= off) ? buf[tid - off] : 0;
        __syncthreads();
        buf[tid] += t;
        __syncthreads();
    }
    growp[tid + 1] = buf[tid];
    gcur[tid] = buf[tid] - v;
    if (tid == 0) growp[0] = 0;
}

__global__ void k_gfill(const int* __restrict__ gid, int* __restrict__ gcur,
                        int* __restrict__ nlist) {
    __shared__ int lcnt[NG];
    __shared__ int lbase[NG];
    int tid = threadIdx.x;
    if (tid < NG) lcnt[tid] = 0;
    __syncthreads();
    int n = blockIdx.x * 1024 + tid;
    int g = -1, rank = 0;
    if (n < NN) { g = gid[n]; rank = atomicAdd(&lcnt[g], 1); }
    __syncthreads();
    if (tid < NG && lcnt[tid] > 0) lbase[tid] = atomicAdd(&gcur[tid], lcnt[tid]);
    __syncthreads();
    if (n < NN) nlist[lbase[g] + rank] = n;
}

// ---------------- fused aggregate + K=512 GEMM -> ab (hx cols 0..127) ----------------
// 256 thr (4 waves), 32 rows/tile (grid 1563).
// Phase 1: wave-uniform segmented gather (see header comment).
// Phase 2: K=512 MFMA (wave w -> rt=w>>1, col-tiles (w&1)*4..+4), + cnt*bs -> ab.
__global__ __launch_bounds__(256) void k_agg_gemm(
    const unsigned short* __restrict__ hx,    // read cols 128..255 (hb)
    const int* __restrict__ rowp4, const int* __restrict__ epk,
    const int* __restrict__ deg4,
    const unsigned short* __restrict__ Wcat,  // 128 x 512 fp16 (out x [t|k])
    const float* __restrict__ bs,             // 4 * 128 fp32
    unsigned short* __restrict__ hxw) {       // write cols 0..127 (ab)
    __shared__ unsigned short Sh[4 * 32 * 136];   // 34.8 KB: plane t, row, col
    __shared__ float Bsb[512];

    const int tid = threadIdx.x;
    const int m0 = blockIdx.x * 32;
    const int wv = tid >> 6;
    const int lane = tid & 63;

    Bsb[tid] = bs[tid];
    Bsb[tid + 256] = bs[tid + 256];
    // zero s-planes (17408 halfs = 8704 dwords)
    {
        unsigned int* z = (unsigned int*)Sh;
#pragma unroll
        for (int i = tid; i < 8704; i += 256) z[i] = 0u;
    }
    __syncthreads();

    // ---- phase 1: wave-uniform segmented gather ----
    {
        const int d2 = lane * 2;
        int n0 = m0 + wv * 8; if (n0 > NN) n0 = NN;
        int n1 = n0 + 8;      if (n1 > NN) n1 = NN;
        const int ebeg = rowp4[n0 * 4];
        const int eend = rowp4[n1 * 4];

        float a0 = 0.f, a1 = 0.f;
        int cur = -1;
        int kq[8];
        int base = ebeg;
#pragma unroll
        for (int j = 0; j < 8; ++j) kq[j] = (base + j < eend) ? epk[base + j] : -1;
        while (base < eend) {
            const int nb2 = base + 8;
            // issue value loads for current chunk (8 in flight)
            f16x2 v[8];
#pragma unroll
            for (int j = 0; j < 8; ++j) {
                int p = kq[j];
                if (p >= 0)
                    v[j] = *(const f16x2*)&hx[(size_t)(p & 0xFFFF) * 256 + 128 + d2];
                else {
                    v[j][0] = (_Float16)0.f; v[j][1] = (_Float16)0.f;
                }
            }
            // prefetch next chunk's keys (overlaps with processing below)
            int kn[8];
#pragma unroll
            for (int j = 0; j < 8; ++j) kn[j] = (nb2 + j < eend) ? epk[nb2 + j] : -1;
            // process (flush branch is wave-uniform)
#pragma unroll
            for (int j = 0; j < 8; ++j) {
                int p = kq[j];
                if (p >= 0) {
                    int key = p >> 16;
                    if (key != cur) {
                        if (cur >= 0) {
                            f16x2 fv; fv[0] = (_Float16)a0; fv[1] = (_Float16)a1;
                            *(f16x2*)&Sh[(cur & 3) * 4352 + (cur >> 2) * 136 + d2] = fv;
                        }
                        cur = key; a0 = 0.f; a1 = 0.f;
                    }
                    a0 += (float)v[j][0];
                    a1 += (float)v[j][1];
                }
            }
#pragma unroll
            for (int j = 0; j < 8; ++j) kq[j] = kn[j];
            base = nb2;
        }
        if (cur >= 0) {
            f16x2 fv; fv[0] = (_Float16)a0; fv[1] = (_Float16)a1;
            *(f16x2*)&Sh[(cur & 3) * 4352 + (cur >> 2) * 136 + d2] = fv;
        }
    }
    __syncthreads();

    // ---- phase 2: K=512 MFMA: wave wv -> rt = wv>>1 (16 rows), col-tiles cts..cts+3
    const int lr = lane & 15;
    const int q = lane >> 4;
    const int rt = wv >> 1;
    const int cts = (wv & 1) * 4;

    f32x4 acc[4];
#pragma unroll
    for (int j = 0; j < 4; ++j) acc[j] = (f32x4){0.f, 0.f, 0.f, 0.f};

#pragma unroll
    for (int ks = 0; ks < 16; ++ks) {
        int t = ks >> 2, ksl = ks & 3;
        f16x8 af = *(const f16x8*)&Sh[t * 4352 + (rt * 16 + lr) * 136 + ksl * 32 + q * 8];
#pragma unroll
        for (int j = 0; j < 4; ++j) {
            f16x8 bf = *(const f16x8*)&Wcat[((cts + j) * 16 + lr) * 512 + ks * 32 + q * 8];
            acc[j] = __builtin_amdgcn_mfma_f32_16x16x32_f16(af, bf, acc[j], 0, 0, 0);
        }
    }

    // epilogue: + sum_t cnt*bs, fp16 store into ab half
    int rowbase = m0 + rt * 16 + q * 4;
#pragma unroll
    for (int rr = 0; rr < 4; ++rr) {
        int n2 = rowbase + rr;
        if (n2 < NN) {
            int4 c = *(const int4*)&deg4[n2 * 4];
            unsigned short* arow = hxw + (size_t)n2 * 256;
#pragma unroll
            for (int j = 0; j < 4; ++j) {
                int col = (cts + j) * 16 + lr;
                float v = acc[j][rr]
                        + c.x * Bsb[col] + c.y * Bsb[128 + col]
                        + c.z * Bsb[256 + col] + c.w * Bsb[384 + col];
                arow[col] = f2h(v);
            }
        }
    }
}

// ---------------- fused gates GEMM + GRU (512 thr, 64 rows, 70.7KB LDS) --------------
// A-tile = hx rows (K=256) staged once. 6 weight chunks (128x128) staged to LDS
// sequentially; MFMA pure-LDS. Wave w owns tiles (rt=w>>1, ct=(w&1)*4+j): accumulates
// R,Z,IN,HN for those tiles -> GRU in-register -> h fp32 + hb half of hx.
__global__ __launch_bounds__(512) void k_gates_gru(
    const unsigned short* __restrict__ hx,
    const unsigned short* __restrict__ Wpk,   // 6 chunks of 128x128 fp16
    const float* __restrict__ bpk,            // 512 packed biases
    float* __restrict__ h,
    unsigned short* __restrict__ hxw) {
    __shared__ unsigned short As[64 * 264];   // 33.8 KB (full 256-col rows, pad 8)
    __shared__ unsigned short Bs[128 * 136];  // 34.8 KB (one weight chunk)
    __shared__ float Bsb[512];

    const int tid = threadIdx.x;
    const int m0 = blockIdx.x * 64;

    Bsb[tid] = bpk[tid];   // 512 threads

    const uint4* H4 = (const uint4*)hx;   // 32 uint4 per 256-half row
#pragma unroll
    for (int it = 0; it < 4; ++it) {
        int i = tid + it * 512;           // 0..2047
        int row = i >> 5, qq = i & 31;
        int nn = m0 + row;
        uint4 v = (nn < NN) ? H4[(size_t)nn * 32 + qq] : make_uint4(0u, 0u, 0u, 0u);
        *(uint4*)&As[row * 264 + qq * 8] = v;
    }

    const int lane = tid & 63;
    const int w = tid >> 6;
    const int lr = lane & 15;
    const int q = lane >> 4;
    const int rt = w >> 1;        // row-tile 0..3
    const int cts = (w & 1) * 4;  // col-tile base

    const uint4* W4 = (const uint4*)Wpk;

    f32x4 accR[4], accZ[4], accI[4], accH[4];
#pragma unroll
    for (int j = 0; j < 4; ++j) {
        accR[j] = (f32x4){0.f, 0.f, 0.f, 0.f};
        accZ[j] = (f32x4){0.f, 0.f, 0.f, 0.f};
        accI[j] = (f32x4){0.f, 0.f, 0.f, 0.f};
        accH[j] = (f32x4){0.f, 0.f, 0.f, 0.f};
    }

#define GCHUNK(C, ACC)                                                              \
    __syncthreads();                                                                \
    _Pragma("unroll")                                                               \
    for (int it = 0; it < 4; ++it) {                                                \
        int i = tid + it * 512;                                                     \
        *(uint4*)&Bs[(i >> 4) * 136 + (i & 15) * 8] = W4[(C) * 2048 + i];           \
    }                                                                               \
    __syncthreads();                                                                \
    _Pragma("unroll")                                                               \
    for (int ks = 0; ks < 4; ++ks) {                                                \
        f16x8 af = *(const f16x8*)&As[(rt * 16 + lr) * 264 + ((C) & 1) * 128        \
                                      + ks * 32 + q * 8];                           \
        _Pragma("unroll")                                                           \
        for (int j = 0; j < 4; ++j) {                                               \
            f16x8 bf = *(const f16x8*)&Bs[((cts + j) * 16 + lr) * 136               \
                                          + ks * 32 + q * 8];                       \
            ACC[j] = __builtin_amdgcn_mfma_f32_16x16x32_f16(af, bf, ACC[j], 0, 0, 0); \
        }                                                                           \
    }

    GCHUNK(0, accR)   // R  += ab . W_ih_r
    GCHUNK(1, accR)   // R  += hb . W_hh_r
    GCHUNK(2, accZ)   // Z  += ab . W_ih_z
    GCHUNK(3, accZ)   // Z  += hb . W_hh_z
    GCHUNK(4, accI)   // IN  = ab . W_ih_n
    GCHUNK(5, accH)   // HN  = hb . W_hh_n
#undef GCHUNK

    // GRU in-register
    int rowb = m0 + rt * 16 + q * 4;
#pragma unroll
    for (int rr = 0; rr < 4; ++rr) {
        int n2 = rowb + rr;
        if (n2 < NN) {
            float* hrow = h + (size_t)n2 * OD;
            unsigned short* hbrow = hxw + (size_t)n2 * 256 + 128;
#pragma unroll
            for (int j = 0; j < 4; ++j) {
                int col = (cts + j) * 16 + lr;
                float R = 1.f / (1.f + __expf(-(accR[j][rr] + Bsb[col])));
                float Z = 1.f / (1.f + __expf(-(accZ[j][rr] + Bsb[128 + col])));
                float NV = tanhf(accI[j][rr] + Bsb[256 + col]
                                 + R * (accH[j][rr] + Bsb[384 + col]));
                float hold = hrow[col];
                float hnew = (1.f - Z) * NV + Z * hold;
                hrow[col] = hnew;
                hbrow[col] = f2h(hnew);
            }
        }
    }
}

// ---------------- graph readout: register acc over graph-sorted node list ------------
__global__ void k_readout(const float* __restrict__ h, const float* __restrict__ nf,
                          const int* __restrict__ nlist, const int* __restrict__ growp,
                          float* __restrict__ partial) {
    int g = blockIdx.x >> 3, c = blockIdx.x & (RC - 1);
    int d = threadIdx.x;
    int s = growp[g], e = growp[g + 1], len = e - s;
    int i0 = s + (int)((long long)len * c / RC);
    int i1 = s + (int)((long long)len * (c + 1) / RC);
    float acc = 0.f;
    for (int i = i0; i < i1; ++i) {
        int n = nlist[i];
        acc += (d < OD) ? h[(size_t)n * OD + d] : nf[(size_t)n * IND + (d - OD)];
    }
    partial[(size_t)blockIdx.x * 192 + d] = acc;
}

__global__ void k_reduce(const float* __restrict__ partial, float* __restrict__ feats) {
    int i = blockIdx.x * 256 + threadIdx.x;
    if (i >= NG * 192) return;
    int g = i / 192, d = i % 192;
    float s = 0.f;
    for (int c = 0; c < RC; ++c) s += partial[(size_t)(g * RC + c) * 192 + d];
    feats[i] = s;
}

__global__ void k_final(const float* __restrict__ feats, const float* __restrict__ W_cls,
                        const float* __restrict__ b_cls, float* __restrict__ out) {
    int g = threadIdx.x;
    if (g >= NG) return;
    float acc = b_cls[0];
    for (int d = 0; d < 192; ++d) acc += feats[g * 192 + d] * W_cls[d];
    out[g] = 1.f / (1.f + __expf(-acc));
}

extern "C" void kernel_launch(void* const* d_in, const int* in_sizes, int n_in,
                              void* d_out, int out_size, void* d_ws, size_t ws_size,
                              hipStream_t stream) {
    const float* nf    = (const float*)d_in[0];
    const int*   src   = (const int*)d_in[1];
    const int*   dst   = (const int*)d_in[2];
    const int*   et    = (const int*)d_in[3];
    const int*   gid   = (const int*)d_in[4];
    const float* Ws    = (const float*)d_in[5];
    const float* bs    = (const float*)d_in[6];
    const float* W_ih  = (const float*)d_in[7];
    const float* W_hh  = (const float*)d_in[8];
    const float* b_ih  = (const float*)d_in[9];
    const float* b_hh  = (const float*)d_in[10];
    const float* W_cls = (const float*)d_in[11];
    const float* b_cls = (const float*)d_in[12];
    float* out = (float*)d_out;

    char* ws = (char*)d_ws;
    size_t off = 0;
    auto alloc = [&](size_t bytes) -> void* {
        off = (off + 255) & ~(size_t)255;
        void* p = ws + off;
        off += bytes;
        return p;
    };
    float*          h    = (float*)alloc((size_t)NN * OD * 4);              // 25.6 MB
    unsigned short* hx   = (unsigned short*)alloc((size_t)NN * 256 * 2);    // 25.6 MB
    int*   deg4    = (int*)alloc((size_t)NN4 * 4);
    int*   rowp4   = (int*)alloc((size_t)(NN4 + 1) * 4);
    int*   cursor4 = (int*)alloc((size_t)NN4 * 4);
    int*   epk     = (int*)alloc((size_t)NE * 4);
    int*   bsum    = (int*)alloc(256 * 4);
    int*   gdeg    = (int*)alloc(NG * 4);
    int*   growp   = (int*)alloc((NG + 1) * 4);
    int*   gcur    = (int*)alloc(NG * 4);
    int*   nlist   = (int*)alloc((size_t)NN * 4);
    float* feats   = (float*)alloc((size_t)NG * 192 * 4);
    float* partial = (float*)alloc((size_t)NG * RC * 192 * 4);              // 393 KB
    unsigned short* Wcat = (unsigned short*)alloc((size_t)65536 * 2);       // 128 KB
    unsigned short* Wpk  = (unsigned short*)alloc((size_t)98304 * 2);       // 192 KB
    float*          bpk  = (float*)alloc(512 * 4);
    (void)ws_size; (void)in_sizes; (void)n_in; (void)out_size;

    hipMemsetAsync(deg4, 0, (size_t)NN4 * 4, stream);
    hipMemsetAsync(gdeg, 0, NG * 4, stream);

    k_cvtws<<<(65536 + 255) / 256, 256, 0, stream>>>(Ws, Wcat);
    k_pack<<<(98304 + 255) / 256, 256, 0, stream>>>(W_ih, W_hh, b_ih, b_hh, Wpk, bpk);

    k_init_h<<<(NN * OD + 255) / 256, 256, 0, stream>>>(nf, h, hx);

    // (dst, etype) CSR
    k_count<<<(NE + 255) / 256, 256, 0, stream>>>(dst, et, deg4);
    const int nb4 = (NN4 + 1023) / 1024;   // 196
    k_scan1<<<nb4, 1024, 0, stream>>>(deg4, rowp4, bsum, NN4);
    k_scan2<<<1, 256, 0, stream>>>(bsum, nb4);
    k_scan3<<<(NN4 + 255) / 256, 256, 0, stream>>>(deg4, bsum, rowp4, cursor4, NN4);
    k_fill<<<(NE + 255) / 256, 256, 0, stream>>>(src, dst, et, cursor4, epk);

    // graph CSR (readout)
    const int nbn = (NN + 1023) / 1024;    // 49
    k_gcount<<<nbn, 1024, 0, stream>>>(gid, gdeg);
    k_gscan<<<1, NG, 0, stream>>>(gdeg, growp, gcur);
    k_gfill<<<nbn, 1024, 0, stream>>>(gid, gcur, nlist);

    const int mt32 = (NN + 31) / 32;   // 1563 node tiles
    const int mt64 = (NN + 63) / 64;   // 782 node tiles
    for (int s = 0; s < 8; ++s) {
        k_agg_gemm<<<mt32, 256, 0, stream>>>(hx, rowp4, epk, deg4, Wcat, bs, hx);
        k_gates_gru<<<mt64, 512, 0, stream>>>(hx, Wpk, bpk, h, hx);
    }

    k_readout<<<NG * RC, 192, 0, stream>>>(h, nf, nlist, growp, partial);
    k_reduce<<<(NG * 192 + 255) / 256, 256, 0, stream>>>(partial, feats);
    k_final<<<1, 64, 0, stream>>>(feats, W_cls, b_cls, out);
}